// Round 15
// baseline (2375.304 us; speedup 1.0000x reference)
//
#include <hip/hip_runtime.h>
#include <math.h>

#define NPIX 262144      // 512*512
#define NQ4  65536       // NPIX/4
#define NIMG 64

__device__ float g_mean[NIMG * 3];
__device__ float g_covacc[NIMG * 6];
__device__ float g_delta[NIMG * 3];

#define M_(a,b) __fmul_rn((a),(b))
#define A_(a,b) __fadd_rn((a),(b))
#define S_(a,b) __fsub_rn((a),(b))
#define D_(a,b) __fdiv_rn((a),(b))
#define Q_(a)   __fsqrt_rn((a))
#define F_(a,b,c) __builtin_fmaf((a),(b),(c))

__device__ __forceinline__ float readlane_f(float v, int l) {
    return __int_as_float(__builtin_amdgcn_readlane(__float_as_int(v), l));
}

// ============ K1: np.mean replica — numpy PAIRWISE summation (reduce axis = inner loop) ======
// pairwise_sum: leaves of 128 elems with 8 accumulators (((r0+r1)+(r2+r3))+((r4+r5)+(r6+r7))),
// recursive halving combine (first half + second half). 262144 = 2^18 -> exact power-of-2 tree.
// Butterfly over 64 consecutive leaves == the same halving tree; chunk tree on top.
__global__ __launch_bounds__(64) void pcacs_mean(const float4* __restrict__ img4) {
#pragma clang fp contract(off)
    int plane = blockIdx.x;          // b*3 + c
    int t = threadIdx.x;
    const float4* P = img4 + (size_t)plane * NQ4;
    __shared__ float lds[64 * 132];  // 64 leaves x 128 floats, padded stride 132

    float chunkS[32];
#pragma unroll
    for (int c = 0; c < 32; ++c) {
        __syncthreads();
#pragma unroll
        for (int k = 0; k < 32; ++k) {
            float4 v = P[c * 2048 + k * 64 + t];
            int fi = k * 64 + t;
            int leaf = fi >> 5;          // 32 float4 per leaf
            int off  = (fi & 31) * 4;
            float* dst = &lds[leaf * 132 + off];
            dst[0] = v.x; dst[1] = v.y; dst[2] = v.z; dst[3] = v.w;
        }
        __syncthreads();
        // numpy pairwise base case (128 elems, 8 accumulators)
        const float* a = &lds[t * 132];
        float r0 = a[0], r1 = a[1], r2 = a[2], r3 = a[3];
        float r4 = a[4], r5 = a[5], r6 = a[6], r7 = a[7];
#pragma unroll
        for (int i = 8; i < 128; i += 8) {
            r0 = A_(r0, a[i + 0]); r1 = A_(r1, a[i + 1]);
            r2 = A_(r2, a[i + 2]); r3 = A_(r3, a[i + 3]);
            r4 = A_(r4, a[i + 4]); r5 = A_(r5, a[i + 5]);
            r6 = A_(r6, a[i + 6]); r7 = A_(r7, a[i + 7]);
        }
        float res = A_(A_(A_(r0, r1), A_(r2, r3)), A_(A_(r4, r5), A_(r6, r7)));
        // halving tree across 64 consecutive leaves (butterfly == recursive halving)
#pragma unroll
        for (int d = 1; d < 64; d <<= 1)
            res = A_(res, __shfl_xor(res, d));
        chunkS[c] = res;
    }
    // top of the halving tree over 32 chunk sums
    float s16[16], s8[8], s4[4], s2[2];
#pragma unroll
    for (int i = 0; i < 16; ++i) s16[i] = A_(chunkS[2 * i], chunkS[2 * i + 1]);
#pragma unroll
    for (int i = 0; i < 8; ++i)  s8[i] = A_(s16[2 * i], s16[2 * i + 1]);
#pragma unroll
    for (int i = 0; i < 4; ++i)  s4[i] = A_(s8[2 * i], s8[2 * i + 1]);
#pragma unroll
    for (int i = 0; i < 2; ++i)  s2[i] = A_(s4[2 * i], s4[2 * i + 1]);
    float tot = A_(s2[0], s2[1]);
    if (t == 0) g_mean[plane] = D_(tot, 262144.0f);   // exact (power of 2)
}

// ============ K2: np.einsum cov replica — SEQUENTIAL f32, one mul+add per pixel ============
// (nditer puts j innermost (count 3, stride0_contig_outcontig); per-entry accumulation over n
//  is strictly sequential ascending — one rn(mul) + rn(add) per pixel, accum from 0.)
__global__ __launch_bounds__(64) void pcacs_cov(const float4* __restrict__ img4) {
#pragma clang fp contract(off)
    int blk = blockIdx.x;                 // img*6 + pair
    int img = blk / 6, pr = blk % 6;
    const int PIc[6] = {0, 0, 0, 1, 1, 2};
    const int PJc[6] = {0, 1, 2, 1, 2, 2};
    int ci = PIc[pr], cj = PJc[pr];
    int l = threadIdx.x;
    const float4* Pi = img4 + (size_t)(img * 3 + ci) * NQ4;
    const float4* Pj = img4 + (size_t)(img * 3 + cj) * NQ4;
    float mi = g_mean[img * 3 + ci], mj = g_mean[img * 3 + cj];

    float acc = 0.0f;
    float4 ca = Pi[l], cb = Pj[l];
    for (int w = 0; w < 1024; ++w) {
        float4 na = ca, nb = cb;
        if (w < 1023) { na = Pi[(w + 1) * 64 + l]; nb = Pj[(w + 1) * 64 + l]; }
        float p0 = M_(S_(ca.x, mi), S_(cb.x, mj));
        float p1 = M_(S_(ca.y, mi), S_(cb.y, mj));
        float p2 = M_(S_(ca.z, mi), S_(cb.z, mj));
        float p3 = M_(S_(ca.w, mi), S_(cb.w, mj));
#pragma unroll
        for (int q = 0; q < 64; ++q) {
            acc = A_(acc, readlane_f(p0, q));
            acc = A_(acc, readlane_f(p1, q));
            acc = A_(acc, readlane_f(p2, q));
            acc = A_(acc, readlane_f(p3, q));
        }
        ca = na; cb = nb;
    }
    if (l == 0) g_covacc[img * 6 + pr] = acc;
}

// ============ LAPACK f32 replicas (netlib ≥3.10 rounding order; Fortran parts NO FMA) ======
__device__ __forceinline__ float fsignf_(float a, float b) {
    return (b >= 0.0f) ? fabsf(a) : -fabsf(a);
}
__device__ float slapy2_(float x, float y) {
#pragma clang fp contract(off)
    float xa = fabsf(x), ya = fabsf(y);
    float w = xa > ya ? xa : ya;
    float z = xa > ya ? ya : xa;
    if (z == 0.0f) return w;
    float q = D_(z, w);
    return M_(w, Q_(A_(1.0f, M_(q, q))));
}
// LAPACK >= 3.10 slartg.f90: d = sqrt(f*f+g*g); p = 1/d; c = |f|*p; s = g*sign(p,f); r = sign(d,f)
__device__ void slartg_(float f, float g, float& c, float& s, float& r) {
#pragma clang fp contract(off)
    if (g == 0.0f)      { c = 1.0f; s = 0.0f; r = f; }
    else if (f == 0.0f) { c = 0.0f; s = (g >= 0.0f) ? 1.0f : -1.0f; r = fabsf(g); }
    else {
        float f1 = fabsf(f);
        float d = Q_(A_(M_(f, f), M_(g, g)));
        float p = D_(1.0f, d);
        c = M_(f1, p);
        float gp = M_(g, p);
        s = (f >= 0.0f) ? gp : -gp;      // g * sign(p, f)
        r = (f >= 0.0f) ? d : -d;        // sign(d, f)
    }
}
__device__ void slaev2_(float a, float b, float c, float& rt1, float& rt2, float& cs1, float& sn1) {
#pragma clang fp contract(off)
    float sm = A_(a, c), df = S_(a, c);
    float adf = fabsf(df);
    float tb = A_(b, b);
    float ab = fabsf(tb);
    float acmx, acmn;
    if (fabsf(a) > fabsf(c)) { acmx = a; acmn = c; } else { acmx = c; acmn = a; }
    float rt;
    if (adf > ab)      { float q = D_(ab, adf); rt = M_(adf, Q_(A_(1.0f, M_(q, q)))); }
    else if (adf < ab) { float q = D_(adf, ab); rt = M_(ab, Q_(A_(1.0f, M_(q, q)))); }
    else               rt = M_(ab, Q_(2.0f));
    int sgn1;
    if (sm < 0.0f) {
        rt1 = M_(0.5f, S_(sm, rt)); sgn1 = -1;
        rt2 = S_(M_(D_(acmx, rt1), acmn), M_(D_(b, rt1), b));
    } else if (sm > 0.0f) {
        rt1 = M_(0.5f, A_(sm, rt)); sgn1 = 1;
        rt2 = S_(M_(D_(acmx, rt1), acmn), M_(D_(b, rt1), b));
    } else { rt1 = M_(0.5f, rt); rt2 = M_(-0.5f, rt); sgn1 = 1; }
    float cs; int sgn2;
    if (df >= 0.0f) { cs = A_(df, rt); sgn2 = 1; } else { cs = S_(df, rt); sgn2 = -1; }
    float acs = fabsf(cs);
    if (acs > ab) {
        float ct = D_(-tb, cs);
        sn1 = D_(1.0f, Q_(A_(1.0f, M_(ct, ct))));
        cs1 = M_(ct, sn1);
    } else {
        if (ab == 0.0f) { cs1 = 1.0f; sn1 = 0.0f; }
        else {
            float tn = D_(-cs, tb);
            cs1 = D_(1.0f, Q_(A_(1.0f, M_(tn, tn))));
            sn1 = M_(tn, cs1);
        }
    }
    if (sgn1 == sgn2) { float tn = cs1; cs1 = -sn1; sn1 = tn; }
}

// ssteqr('I', n=3), f32, exact LAPACK expression order
__device__ void ssteqr3_(float* d, float* e, float z[4][4]) {
#pragma clang fp contract(off)
    const int n = 3;
    const float eps = 5.9604645e-8f;           // 2^-24
    const float eps2 = M_(eps, eps);
    const float safmin = 1.17549435e-38f;
    float wc[3], wsv[3];
    for (int i = 1; i <= 3; ++i)
        for (int j = 1; j <= 3; ++j) z[i][j] = (i == j) ? 1.0f : 0.0f;
    const int nmaxit = n * 30;
    int jtot = 0, l1 = 1;
    const int nm1 = n - 1;
    int l, lsv, lend, lendsv, m;
    float p, g, r, c, s, f, b, anorm, rt1, rt2;

L10:
    if (l1 > n) goto L160;
    if (l1 > 1) e[l1 - 1] = 0.0f;
    if (l1 <= nm1) {
        for (m = l1; m <= nm1; ++m) {
            float tst = fabsf(e[m]);
            if (tst == 0.0f) goto L30;
            if (tst <= M_(M_(Q_(fabsf(d[m])), Q_(fabsf(d[m + 1]))), eps)) { e[m] = 0.0f; goto L30; }
        }
    }
    m = n;
L30:
    l = l1; lsv = l; lend = m; lendsv = lend; l1 = m + 1;
    if (lend == l) goto L10;
    anorm = 0.0f;
    for (int i = l; i <= lend; ++i) anorm = fmaxf(anorm, fabsf(d[i]));
    for (int i = l; i <= lend - 1; ++i) anorm = fmaxf(anorm, fabsf(e[i]));
    if (anorm == 0.0f) goto L10;
    if (fabsf(d[lend]) < fabsf(d[l])) { lend = lsv; l = lendsv; }
    if (lend > l) {
        // ---- QL ----
L40:
        if (l != lend) {
            for (m = l; m <= lend - 1; ++m) {
                float tst = M_(e[m], e[m]);
                if (tst <= A_(M_(M_(eps2, fabsf(d[m])), fabsf(d[m + 1])), safmin)) goto L60;
            }
        }
        m = lend;
L60:
        if (m < lend) e[m] = 0.0f;
        p = d[l];
        if (m == l) goto L80;
        if (m == l + 1) {
            slaev2_(d[l], e[l], d[l + 1], rt1, rt2, c, s);
            for (int i = 1; i <= n; ++i) {
                float temp = z[i][l + 1];
                z[i][l + 1] = S_(M_(c, temp), M_(s, z[i][l]));
                z[i][l]     = A_(M_(s, temp), M_(c, z[i][l]));
            }
            d[l] = rt1; d[l + 1] = rt2; e[l] = 0.0f;
            l += 2;
            if (l <= lend) goto L40;
            goto L140;
        }
        if (jtot == nmaxit) goto L140;
        jtot++;
        g = D_(S_(d[l + 1], p), M_(2.0f, e[l]));
        r = slapy2_(g, 1.0f);
        g = A_(S_(d[m], p), D_(e[l], A_(g, fsignf_(r, g))));
        s = 1.0f; c = 1.0f; p = 0.0f;
        for (int i = m - 1; i >= l; --i) {
            f = M_(s, e[i]);
            b = M_(c, e[i]);
            slartg_(g, f, c, s, r);
            if (i != m - 1) e[i + 1] = r;
            g = S_(d[i + 1], p);
            r = A_(M_(S_(d[i], g), s), M_(M_(2.0f, c), b));
            p = M_(s, r);
            d[i + 1] = A_(g, p);
            g = S_(M_(c, r), b);
            wc[i] = c; wsv[i] = -s;
        }
        {
            int mm = m - l + 1;   // slasr 'R','V','B'
            for (int jj = mm - 1; jj >= 1; --jj) {
                float ct = wc[l + jj - 1], st = wsv[l + jj - 1];
                for (int i = 1; i <= n; ++i) {
                    float temp = z[i][l + jj];
                    z[i][l + jj]     = S_(M_(ct, temp), M_(st, z[i][l + jj - 1]));
                    z[i][l + jj - 1] = A_(M_(st, temp), M_(ct, z[i][l + jj - 1]));
                }
            }
        }
        d[l] = S_(d[l], p);
        e[l] = g;
        goto L40;
L80:
        d[l] = p;
        l++;
        if (l <= lend) goto L40;
        goto L140;
    } else {
        // ---- QR ----
L90:
        if (l != lend) {
            for (m = l; m >= lend + 1; --m) {
                float tst = M_(e[m - 1], e[m - 1]);
                if (tst <= A_(M_(M_(eps2, fabsf(d[m])), fabsf(d[m - 1])), safmin)) goto L110;
            }
        }
        m = lend;
L110:
        if (m > lend) e[m - 1] = 0.0f;
        p = d[l];
        if (m == l) goto L130;
        if (m == l - 1) {
            slaev2_(d[l - 1], e[l - 1], d[l], rt1, rt2, c, s);
            for (int i = 1; i <= n; ++i) {
                float temp = z[i][l];
                z[i][l]     = S_(M_(c, temp), M_(s, z[i][l - 1]));
                z[i][l - 1] = A_(M_(s, temp), M_(c, z[i][l - 1]));
            }
            d[l - 1] = rt1; d[l] = rt2; e[l - 1] = 0.0f;
            l -= 2;
            if (l >= lend) goto L90;
            goto L140;
        }
        if (jtot == nmaxit) goto L140;
        jtot++;
        g = D_(S_(d[l - 1], p), M_(2.0f, e[l - 1]));
        r = slapy2_(g, 1.0f);
        g = A_(S_(d[m], p), D_(e[l - 1], A_(g, fsignf_(r, g))));
        s = 1.0f; c = 1.0f; p = 0.0f;
        for (int i = m; i <= l - 1; ++i) {
            f = M_(s, e[i]);
            b = M_(c, e[i]);
            slartg_(g, f, c, s, r);
            if (i != m) e[i - 1] = r;
            g = S_(d[i], p);
            r = A_(M_(S_(d[i + 1], g), s), M_(M_(2.0f, c), b));
            p = M_(s, r);
            d[i] = A_(g, p);
            g = S_(M_(c, r), b);
            wc[i] = c; wsv[i] = s;
        }
        {
            int mm = l - m + 1;   // slasr 'R','V','F'
            for (int jj = 1; jj <= mm - 1; ++jj) {
                float ct = wc[m + jj - 1], st = wsv[m + jj - 1];
                for (int i = 1; i <= n; ++i) {
                    float temp = z[i][m + jj];
                    z[i][m + jj]     = S_(M_(ct, temp), M_(st, z[i][m + jj - 1]));
                    z[i][m + jj - 1] = A_(M_(st, temp), M_(ct, z[i][m + jj - 1]));
                }
            }
        }
        d[l] = S_(d[l], p);
        e[l - 1] = g;
        goto L90;
L130:
        d[l] = p;
        l--;
        if (l >= lend) goto L90;
        goto L140;
    }
L140:
    if (jtot < nmaxit) goto L10;
    return;
L160:
    for (int ii = 2; ii <= n; ++ii) {
        int i = ii - 1, k = i;
        float pp = d[i];
        for (int jj = ii; jj <= n; ++jj)
            if (d[jj] < pp) { k = jj; pp = d[jj]; }
        if (k != i) {
            d[k] = d[i]; d[i] = pp;
            for (int rr = 1; rr <= 3; ++rr) { float tt = z[rr][i]; z[rr][i] = z[rr][k]; z[rr][k] = tt; }
        }
    }
}

// ============ K3: ssyevd replica (f32 flow; OpenBLAS BLAS-kernel sites FMA'd) ======
__global__ __launch_bounds__(64) void pcacs_solve(const float* __restrict__ alphas) {
#pragma clang fp contract(off)
    int img = blockIdx.x;
    if (threadIdx.x != 0) return;

    float cov[6];
#pragma unroll
    for (int k = 0; k < 6; ++k)
        cov[k] = D_(g_covacc[img * 6 + k], 262143.0f);
    float a00 = cov[0], a01 = cov[1], a02 = cov[2], a11 = cov[3], a12 = cov[4], a22 = cov[5];

    // ---- ssytd2 (lower, n=3) ----
    float dd[4], ee[3], tau, v2;
    {
        float alpha = a01;   // A(2,1)
        float x     = a02;   // A(3,1)
        float A11 = a11, A21 = a12, A22 = a22;
        if (x == 0.0f) {
            tau = 0.0f; v2 = 0.0f; ee[1] = alpha;
        } else {
            float xnorm = fabsf(x);
            float beta = -fsignf_(slapy2_(alpha, xnorm), alpha);
            tau = D_(S_(beta, alpha), beta);
            float sc = D_(1.0f, S_(alpha, beta));
            v2 = M_(x, sc);
            ee[1] = beta;
            // ssymv lower n=2 (FMA): w = tau*A*v, v=(1,v2)
            float w1 = M_(tau, A11);
            float w2 = M_(tau, A21);
            float temp2 = M_(A21, v2);
            w1 = F_(tau, temp2, w1);
            w2 = F_(M_(tau, v2), A22, w2);
            // sdot (FMA)
            float dot = F_(w2, v2, w1);
            float alc = M_(M_(-0.5f, tau), dot);
            // saxpy (FMA)
            w1 = A_(w1, alc);
            w2 = F_(alc, v2, w2);
            // ssyr2 lower n=2, alpha=-1 (FMA chains)
            A11 = S_(S_(A11, w1), w1);
            A21 = S_(F_(v2, -w1, A21), w2);
            A22 = F_(w2, -v2, F_(v2, -w2, A22));
        }
        ee[2] = A21;
        dd[1] = a00; dd[2] = A11; dd[3] = A22;
    }

    float z[4][4];
    ssteqr3_(dd, ee, z);

    // ---- sormtr -> slarf('L'): sgemv('T') + sger (FMA) ----
    float negtau = -tau;
    for (int j = 1; j <= 3; ++j) {
        float wj = F_(z[3][j], v2, z[2][j]);
        float tmp = M_(negtau, wj);
        z[2][j] = A_(z[2][j], tmp);
        z[3][j] = F_(v2, tmp, z[3][j]);
    }

    // ---- delta: einsum count=3 scalar tail, ascending j over the descending arrays ----
    float al0 = alphas[img * 3 + 0], al1 = alphas[img * 3 + 1], al2 = alphas[img * 3 + 2];
    float av0 = M_(al0, dd[3]);   // desc j=0 = asc 2
    float av1 = M_(al1, dd[2]);
    float av2 = M_(al2, dd[1]);   // desc j=2 = asc 0
#pragma unroll
    for (int i = 0; i < 3; ++i) {
        float p0 = M_(z[i + 1][3], av0);   // desc j=0
        float p1 = M_(z[i + 1][2], av1);   // desc j=1
        float p2 = M_(z[i + 1][1], av2);   // desc j=2
        g_delta[img * 3 + i] = A_(A_(p0, p1), p2);
    }
}

// ============ K4: out = clip((x - m) + d + m, 0, 255) ============
__global__ __launch_bounds__(256) void pcacs_apply(const float4* __restrict__ in4,
                                                   float4* __restrict__ out4) {
#pragma clang fp contract(off)
    int i = blockIdx.x * blockDim.x + threadIdx.x;
    int bc = i >> 16;
    float dv = g_delta[bc];
    float mv = g_mean[bc];
    float4 v = in4[i];
    float4 o;
    o.x = fminf(fmaxf(A_(A_(S_(v.x, mv), dv), mv), 0.0f), 255.0f);
    o.y = fminf(fmaxf(A_(A_(S_(v.y, mv), dv), mv), 0.0f), 255.0f);
    o.z = fminf(fmaxf(A_(A_(S_(v.z, mv), dv), mv), 0.0f), 255.0f);
    o.w = fminf(fmaxf(A_(A_(S_(v.w, mv), dv), mv), 0.0f), 255.0f);
    out4[i] = o;
}

extern "C" void kernel_launch(void* const* d_in, const int* in_sizes, int n_in,
                              void* d_out, int out_size, void* d_ws, size_t ws_size,
                              hipStream_t stream) {
    const float* images = (const float*)d_in[0];
    const float* alphas = (const float*)d_in[1];
    float* out = (float*)d_out;

    pcacs_mean<<<NIMG * 3, 64, 0, stream>>>((const float4*)images);
    pcacs_cov<<<NIMG * 6, 64, 0, stream>>>((const float4*)images);
    pcacs_solve<<<NIMG, 64, 0, stream>>>(alphas);
    int total4 = NIMG * 3 * NQ4;
    pcacs_apply<<<total4 / 256, 256, 0, stream>>>((const float4*)images, (float4*)out);
}